// Round 5
// baseline (600.162 us; speedup 1.0000x reference)
//
#include <hip/hip_runtime.h>
#include <hip/hip_fp16.h>

#define NFEAT 5
#define HID 64
#define BSH 11              // bucket = dst >> 11 (2048 nodes/bucket)
#define NBK 64              // allocated buckets (49 used for n=100000)
#define CHUNK 2048          // edges per bin block

// ---------------- CSR build ----------------
__global__ void k_zero(int* p, int n) {
    int i = blockIdx.x * blockDim.x + threadIdx.x;
    if (i < n) p[i] = 0;
}

__global__ void k_hist(const int* __restrict__ dst, int* cnt, int E) {
    int e = blockIdx.x * blockDim.x + threadIdx.x;
    if (e < E) atomicAdd(&cnt[dst[e]], 1);
}

// dis[i] = rsqrt(deg) ; xs[i,:] = dis[i] * x[i,:]
__global__ void k_dis_xscale(const int* __restrict__ cnt, const float* __restrict__ x,
                             float* dis, float* xs, int n) {
    int i = blockIdx.x * blockDim.x + threadIdx.x;
    if (i >= n) return;
    float d = rsqrtf((float)cnt[i] + 1.0f);   // +1 self-loop
    dis[i] = d;
#pragma unroll
    for (int c = 0; c < NFEAT; ++c) xs[i * NFEAT + c] = d * x[i * NFEAT + c];
}

// ---- 3-phase exclusive scan of cnt[0..n) -> rp[0..n] ----
__global__ void k_scan_partial(const int* __restrict__ cnt, int* part, int n) {
    __shared__ int sh[256];
    int t = threadIdx.x, gid = blockIdx.x * 256 + t;
    sh[t] = (gid < n) ? cnt[gid] : 0;
    __syncthreads();
    for (int off = 128; off > 0; off >>= 1) {
        if (t < off) sh[t] += sh[t + off];
        __syncthreads();
    }
    if (t == 0) part[blockIdx.x] = sh[0];
}

__global__ void k_scan_part(int* part, int nb) {   // single block, exclusive in place
    __shared__ int sh[1024];
    int t = threadIdx.x;
    int v = (t < nb) ? part[t] : 0;
    sh[t] = v;
    __syncthreads();
    for (int off = 1; off < 1024; off <<= 1) {
        int a = (t >= off) ? sh[t - off] : 0;
        __syncthreads();
        sh[t] += a;
        __syncthreads();
    }
    if (t < nb) part[t] = sh[t] - v;
}

__global__ void k_scan_final(const int* __restrict__ cnt, const int* __restrict__ part,
                             int* rp, int n) {
    __shared__ int sh[256];
    int t = threadIdx.x, gid = blockIdx.x * 256 + t;
    int v = (gid < n) ? cnt[gid] : 0;
    sh[t] = v;
    __syncthreads();
    for (int off = 1; off < 256; off <<= 1) {
        int a = (t >= off) ? sh[t - off] : 0;
        __syncthreads();
        sh[t] += a;
        __syncthreads();
    }
    if (gid < n)      rp[gid] = part[blockIdx.x] + sh[t] - v;
    if (gid == n - 1) rp[n]   = part[blockIdx.x] + sh[t];
}

__global__ void k_bcur(const int* __restrict__ rp, int* bcur, int n) {
    int t = threadIdx.x;   // 64 threads
    int idx = t << BSH;
    if (idx > n) idx = n;
    bcur[t] = rp[idx];
}

// bin edges by dst>>BSH with LDS multi-split; output runs are bucket-contiguous
__global__ __launch_bounds__(256) void
k_bin(const int* __restrict__ src, const int* __restrict__ dst,
      int* bcur, int2* __restrict__ binned, int E) {
    __shared__ int2 stg[CHUNK];
    __shared__ int hist[NBK], base[NBK], gb[NBK];
    int t = threadIdx.x;
    int e0 = blockIdx.x * CHUNK;
    int cc = E - e0; if (cc > CHUNK) cc = CHUNK;
    if (t < NBK) hist[t] = 0;
    __syncthreads();
    int2 my[CHUNK / 256]; int mb[CHUNK / 256];
#pragma unroll
    for (int k = 0; k < CHUNK / 256; ++k) {
        int i = e0 + k * 256 + t;
        if (i < E) {
            my[k].x = src[i]; my[k].y = dst[i];
            mb[k] = my[k].y >> BSH;
            atomicAdd(&hist[mb[k]], 1);
        } else mb[k] = -1;
    }
    __syncthreads();
    if (t < NBK) {     // threads 0..63 == wave 0: exclusive scan + global reserve
        int c = hist[t];
        int x = c;
#pragma unroll
        for (int off = 1; off < 64; off <<= 1) {
            int y = __shfl_up(x, off, 64);
            if (t >= off) x += y;
        }
        base[t] = x - c;
        gb[t] = (c > 0) ? atomicAdd(&bcur[t], c) : 0;
        hist[t] = 0;   // reuse as placement cursor
    }
    __syncthreads();
#pragma unroll
    for (int k = 0; k < CHUNK / 256; ++k) {
        if (mb[k] >= 0) {
            int p = base[mb[k]] + atomicAdd(&hist[mb[k]], 1);
            stg[p] = my[k];
        }
    }
    __syncthreads();
#pragma unroll
    for (int k = 0; k < CHUNK / 256; ++k) {
        int p = k * 256 + t;
        if (p < cc) {
            int2 v = stg[p];
            int b = v.y >> BSH;
            binned[gb[b] + (p - base[b])] = v;
        }
    }
}

// local fill: binned edges are bucket-grouped -> csr writes stay in L2-resident windows
__global__ void k_fill2(const int2* __restrict__ binned, const int* __restrict__ rp,
                        int* cursor, int* __restrict__ csr, int E) {
    int i = blockIdx.x * blockDim.x + threadIdx.x;
    if (i >= E) return;
    int2 v = binned[i];
    int pos = rp[v.y] + atomicAdd(&cursor[v.y], 1);
    csr[pos] = v.x;
}

// ---------------- layer 1 fused: gather xs (5-wide) + GEMM 5->64 + relu, g1h=fp16(dis*h1) ----
__global__ void k_layer1(const int* __restrict__ rp, const int* __restrict__ csr,
                         const float* __restrict__ xs, const float* __restrict__ dis,
                         const float* __restrict__ W1, const float* __restrict__ b1,
                         __half* __restrict__ g1h, int n) {
    int wave = (blockIdx.x * blockDim.x + threadIdx.x) >> 6;
    int lane = threadIdx.x & 63;
    if (wave >= n) return;
    int v = wave;
    int r0 = rp[v], r1 = rp[v + 1];
    float a0 = 0.f, a1 = 0.f, a2 = 0.f, a3 = 0.f, a4 = 0.f;
    for (int j = r0 + lane; j < r1; j += 64) {
        const float* p = xs + (size_t)csr[j] * NFEAT;
        a0 += p[0]; a1 += p[1]; a2 += p[2]; a3 += p[3]; a4 += p[4];
    }
#pragma unroll
    for (int m = 32; m > 0; m >>= 1) {
        a0 += __shfl_xor(a0, m, 64); a1 += __shfl_xor(a1, m, 64);
        a2 += __shfl_xor(a2, m, 64); a3 += __shfl_xor(a3, m, 64);
        a4 += __shfl_xor(a4, m, 64);
    }
    float dv = dis[v];
    const float* pv = xs + (size_t)v * NFEAT;
    a0 = dv * (a0 + pv[0]); a1 = dv * (a1 + pv[1]); a2 = dv * (a2 + pv[2]);
    a3 = dv * (a3 + pv[3]); a4 = dv * (a4 + pv[4]);
    int c = lane;
    float h = b1[c] + a0 * W1[c] + a1 * W1[64 + c] + a2 * W1[128 + c]
            + a3 * W1[192 + c] + a4 * W1[256 + c];
    g1h[(size_t)v * HID + c] = __float2half(dv * fmaxf(h, 0.0f));
}

// ------- layer 2+3 fused: shfl-broadcast indices, half2 gather (2 edges/inst) -------
// lanes 0-31 = even edge, lanes 32-63 = odd edge; lane covers channels (2m, 2m+1)
__global__ __launch_bounds__(256) void
k_layer23(const int* __restrict__ rp, const int* __restrict__ csr,
          const __half2* __restrict__ g1h2, const float* __restrict__ dis,
          const float* __restrict__ W2, const float* __restrict__ b2,
          const float* __restrict__ W3, float* __restrict__ svs, int n) {
    __shared__ float2 W2pk[32 * HID];   // W2pk[m*64+c] = (W2[2m][c], W2[2m+1][c])
    for (int i = threadIdx.x; i < 32 * HID; i += 256) {
        int mm = i >> 6, c = i & 63;
        W2pk[i] = make_float2(W2[((2 * mm) << 6) + c], W2[((2 * mm + 1) << 6) + c]);
    }
    __syncthreads();
    int wave = (blockIdx.x * blockDim.x + threadIdx.x) >> 6;
    int lane = threadIdx.x & 63;
    if (wave >= n) return;
    int v = wave;
    int r0 = rp[v], r1 = rp[v + 1];
    int len = r1 - r0;
    int m = lane & 31;      // channel pair index
    int h = lane >> 5;      // edge half
    float2 acc = make_float2(0.f, 0.f);
    for (int base = 0; base < len; base += 64) {
        int cc = len - base; if (cc > 64) cc = 64;
        // one coalesced load covers up to 64 neighbor indices
        int idx = csr[r0 + base + ((lane < cc) ? lane : (cc - 1))];
        int e = 0;
#pragma unroll 4
        for (; e + 2 <= cc; e += 2) {
            int s = __shfl(idx, e + h, 64);                   // broadcast, no memory
            float2 f = __half22float2(g1h2[(size_t)s * 32 + m]);
            acc.x += f.x; acc.y += f.y;
        }
        if (e < cc) {                                          // odd tail edge
            int s = __shfl(idx, e, 64);
            if (h == 0) {
                float2 f = __half22float2(g1h2[(size_t)s * 32 + m]);
                acc.x += f.x; acc.y += f.y;
            }
        }
    }
    // self term (counted once via h==0)
    if (h == 0) {
        float2 f = __half22float2(g1h2[(size_t)v * 32 + m]);
        acc.x += f.x; acc.y += f.y;
    }
    // combine the two edge-halves: lanes l and l^32 hold same channel pair
    acc.x += __shfl_xor(acc.x, 32, 64);
    acc.y += __shfl_xor(acc.y, 32, 64);
    float dv = dis[v];
    acc.x *= dv; acc.y *= dv;                // agg2[v, 2m], agg2[v, 2m+1] (all lanes)
    // h2[v,c] = relu(b2[c] + sum_k agg[k] * W2[k,c]) ; lane c holds out[c]
    float out = b2[lane];
#pragma unroll
    for (int mm = 0; mm < 32; ++mm) {
        float ax = __shfl(acc.x, mm, 64);
        float ay = __shfl(acc.y, mm, 64);
        float2 w = W2pk[(mm << 6) + lane];
        out += ax * w.x + ay * w.y;
    }
    out = fmaxf(out, 0.0f);
    float val = out * W3[lane];
#pragma unroll
    for (int mm2 = 32; mm2 > 0; mm2 >>= 1) val += __shfl_xor(val, mm2, 64);
    if (lane == 0) svs[v] = dv * val;        // pre-scaled for output gather
}

// ---------------- output: gather scalars ----------------
__global__ void k_out(const int* __restrict__ rp, const int* __restrict__ csr,
                      const float* __restrict__ svs, const float* __restrict__ dis,
                      const float* __restrict__ b3, float* __restrict__ out, int n) {
    int wave = (blockIdx.x * blockDim.x + threadIdx.x) >> 6;
    int lane = threadIdx.x & 63;
    if (wave >= n) return;
    int v = wave;
    int r0 = rp[v], r1 = rp[v + 1];
    float acc = (lane == 0) ? svs[v] : 0.f;            // self term
    for (int j = r0 + lane; j < r1; j += 64) acc += svs[csr[j]];
#pragma unroll
    for (int mm = 32; mm > 0; mm >>= 1) acc += __shfl_xor(acc, mm, 64);
    if (lane == 0) out[v] = b3[0] + dis[v] * acc;
}

extern "C" void kernel_launch(void* const* d_in, const int* in_sizes, int n_in,
                              void* d_out, int out_size, void* d_ws, size_t ws_size,
                              hipStream_t stream) {
    const float* x  = (const float*)d_in[0];
    const int*   ei = (const int*)d_in[1];
    const float* W1 = (const float*)d_in[2];
    const float* b1 = (const float*)d_in[3];
    const float* W2 = (const float*)d_in[4];
    const float* b2 = (const float*)d_in[5];
    const float* W3 = (const float*)d_in[6];
    const float* b3 = (const float*)d_in[7];
    float* out = (float*)d_out;

    const int n = out_size;           // 100000
    const int E = in_sizes[1] / 2;    // 3200000
    const int* src = ei;
    const int* dst = ei + E;

    // ws layout (4B units):
    // cnt[n] cur[n] rp[n+2] dis[n] svs[n] part[1024] bcur[64] csr[E] binned[2E] xs[5n]
    // g1h aliases binned (dead after k_fill2); 64n halves = 32n ints <= 2E ints.
    int*    cnt    = (int*)d_ws;
    int*    cur    = cnt + n;
    int*    rp     = cur + n;
    float*  dis    = (float*)(rp + n + 2);
    float*  svs    = dis + n;
    int*    part   = (int*)(svs + n);
    int*    bcur   = part + 1024;
    int*    csr    = bcur + 64;
    int2*   binned = (int2*)(csr + E);
    float*  xs     = (float*)(binned + E);
    __half* g1h    = (__half*)binned;

    const int B = 256;
    const int gridE = (E + B - 1) / B;
    const int gridN = (n + B - 1) / B;
    const int gridW = (n * 64 + B - 1) / B;   // one wave per node
    const int nb    = (n + 255) / 256;        // scan blocks (391)
    const int gridB = (E + CHUNK - 1) / CHUNK;

    k_zero        <<<(2 * n + B - 1) / B, B, 0, stream>>>(cnt, 2 * n);  // cnt + cursor
    k_hist        <<<gridE, B, 0, stream>>>(dst, cnt, E);
    k_dis_xscale  <<<gridN, B, 0, stream>>>(cnt, x, dis, xs, n);
    k_scan_partial<<<nb, 256, 0, stream>>>(cnt, part, n);
    k_scan_part   <<<1, 1024, 0, stream>>>(part, nb);
    k_scan_final  <<<nb, 256, 0, stream>>>(cnt, part, rp, n);
    k_bcur        <<<1, 64, 0, stream>>>(rp, bcur, n);
    k_bin         <<<gridB, 256, 0, stream>>>(src, dst, bcur, binned, E);
    k_fill2       <<<gridE, B, 0, stream>>>(binned, rp, cur, csr, E);

    k_layer1      <<<gridW, B, 0, stream>>>(rp, csr, xs, dis, W1, b1, g1h, n);
    k_layer23     <<<gridW, B, 0, stream>>>(rp, csr, (const __half2*)g1h, dis, W2, b2, W3, svs, n);
    k_out         <<<gridW, B, 0, stream>>>(rp, csr, svs, dis, b3, out, n);
}